// Round 1
// baseline (213.759 us; speedup 1.0000x reference)
//
#include <hip/hip_runtime.h>
#include <math.h>

#define NB   16
#define CIN  256
#define FW   76
#define FF   (FW*FW)          // 5776
#define NT   50
#define NA   3
#define NCH  85               // 80 classes + 5
#define POSB 256
#define NCONV ((FF + POSB - 1)/POSB)   // 23
#define CONV_BLOCKS (NB*NCONV)         // 368
#define TGT_BLOCKS  (NB*NT)            // 800

__device__ __constant__ float c_aw[9] = {1.25f,2.0f,4.125f,3.75f,7.75f,7.375f,14.5f,19.5f,46.625f};
__device__ __constant__ float c_ah[9] = {1.625f,3.75f,2.875f,7.625f,5.625f,14.875f,11.25f,24.75f,40.75f};

__device__ inline float clogf_(float z){
  return (z > 0.f) ? fmaxf(logf(z), -100.f) : -100.f;
}
__device__ inline float sigmoidf_(float z){
  return 1.f/(1.f + expf(-z));
}

struct TInfo {
  int valid, keep, la, gxi, gyi, cls;
  float gx, gy, gw, gh;
};

__device__ inline TInfo make_tinfo(const float* __restrict__ tg, int b, int t){
  const float* p = tg + ((size_t)b*NT + t)*5;
  float x=p[0], y=p[1], w=p[2], h=p[3], c=p[4];
  TInfo r;
  r.valid = (x+y+w+h+c) > 0.f ? 1 : 0;
  r.gx = x*(float)FW; r.gy = y*(float)FW; r.gw = w*(float)FW; r.gh = h*(float)FW;
  r.gxi = (int)r.gx; r.gyi = (int)r.gy;
  r.cls = (int)c;
  int best=0; float br=-1.f;
  #pragma unroll
  for (int i=0;i<9;++i){
    float inter = fminf(r.gw, c_aw[i]) * fminf(r.gh, c_ah[i]);
    float uni = r.gw*r.gh + c_aw[i]*c_ah[i] - inter;
    float rt = inter/(uni + 1e-16f);
    if (rt > br){ br = rt; best = i; }
  }
  r.la = best;
  r.keep = (r.valid && best < NA) ? 1 : 0;
  return r;
}

__global__ __launch_bounds__(256) void yolo_fused(
    const float* __restrict__ x, const float* __restrict__ tg,
    const float* __restrict__ W, const float* __restrict__ bias,
    double* __restrict__ accum)
{
  const int bid = blockIdx.x;
  const int tid = threadIdx.x;

  if (bid < CONV_BLOCKS) {
    // ---------- dense pass: obj loss over all cells (only 15 conv channels) ----------
    const int b   = bid / NCONV;
    const int pos = (bid % NCONV)*POSB + tid;
    const bool act = pos < FF;
    const int posc = act ? pos : 0;

    __shared__ float s_x1[NT], s_y1[NT], s_x2[NT], s_y2[NT], s_area[NT];
    __shared__ int   s_val[NT], s_code[NT];
    __shared__ int   s_nt;
    __shared__ float s_red[POSB];

    int myvalid = 0;
    if (tid < NT) {
      TInfo ti = make_tinfo(tg, b, tid);
      myvalid = ti.valid;
      s_val[tid]  = ti.valid;
      s_x1[tid]   = ti.gx - 0.5f*ti.gw;
      s_x2[tid]   = ti.gx + 0.5f*ti.gw;
      s_y1[tid]   = ti.gy - 0.5f*ti.gh;
      s_y2[tid]   = ti.gy + 0.5f*ti.gh;
      s_area[tid] = ti.gw*ti.gh;
      s_code[tid] = ti.keep ? (ti.la*FF + ti.gyi*FW + ti.gxi) : -1;
    }
    if (tid < 64) {
      unsigned long long m = __ballot(myvalid != 0);
      if (tid == 0) s_nt = __popcll(m);
    }
    __syncthreads();

    // conv: 15 output channels (3 anchors x {x,y,w,h,conf})
    float acc[NA][5];
    #pragma unroll
    for (int a=0;a<NA;++a)
      #pragma unroll
      for (int c=0;c<5;++c) acc[a][c] = 0.f;

    const float* __restrict__ xp = x + (size_t)b*CIN*FF + posc;
    for (int k0=0; k0<CIN; k0+=8) {
      float xv[8];
      #pragma unroll
      for (int j=0;j<8;++j) xv[j] = xp[(size_t)(k0+j)*FF];
      #pragma unroll
      for (int j=0;j<8;++j) {
        const int k = k0 + j;
        #pragma unroll
        for (int a=0;a<NA;++a)
          #pragma unroll
          for (int c=0;c<5;++c)
            acc[a][c] = fmaf(xv[j], W[(size_t)(a*NCH+c)*CIN + k], acc[a][c]);
      }
    }

    float lobj = 0.f;
    if (act) {
      const int gx = pos % FW;
      const int gy = pos / FW;
      #pragma unroll
      for (int a=0;a<NA;++a) {
        const float z0 = acc[a][0] + bias[a*NCH+0];
        const float z1 = acc[a][1] + bias[a*NCH+1];
        const float z2 = acc[a][2] + bias[a*NCH+2];
        const float z3 = acc[a][3] + bias[a*NCH+3];
        const float z4 = acc[a][4] + bias[a*NCH+4];
        const float s0 = sigmoidf_(z0);
        const float s1 = sigmoidf_(z1);
        const float s4 = sigmoidf_(z4);
        const float px = s0 + (float)gx;
        const float py = s1 + (float)gy;
        const float pw = expf(z2)*c_aw[a];
        const float ph = expf(z3)*c_ah[a];
        const float px1 = px - 0.5f*pw, px2 = px + 0.5f*pw;
        const float py1 = py - 0.5f*ph, py2 = py + 0.5f*ph;
        const float parea = pw*ph;
        bool high = false, ist = false;
        const int code = a*FF + pos;
        for (int t=0;t<NT;++t) {
          if (s_val[t]) {
            float iw = fminf(px2, s_x2[t]) - fmaxf(px1, s_x1[t]); iw = fmaxf(iw, 0.f);
            float ih = fminf(py2, s_y2[t]) - fmaxf(py1, s_y1[t]); ih = fmaxf(ih, 0.f);
            float ia = iw*ih;
            float iou = ia / (parea + s_area[t] - ia + 1e-16f);
            high = high || (iou > 0.7f);
          }
          ist = ist || (s_code[t] == code);
        }
        float mask = ist ? 1.f : ((a < s_nt) ? (high ? 0.f : 1.f) : 1.f);
        if (mask != 0.f)
          lobj -= ist ? clogf_(s4) : clogf_(1.f - s4);
      }
    }

    s_red[tid] = lobj;
    __syncthreads();
    #pragma unroll
    for (int s=POSB/2; s>0; s>>=1) {
      if (tid < s) s_red[tid] += s_red[tid+s];
      __syncthreads();
    }
    if (tid == 0) atomicAdd(accum+2, (double)s_red[0]);

  } else {
    // ---------- target pass: xy/wh/cls at the <=800 target cells ----------
    const int idx = bid - CONV_BLOCKS;
    const int b = idx / NT, t = idx % NT;
    TInfo ti = make_tinfo(tg, b, t);
    if (!ti.keep) return;                 // uniform over the block
    const int a   = ti.la;
    const int pos = ti.gyi*FW + ti.gxi;

    __shared__ float xs[CIN];
    __shared__ float sdot[NCH*3];
    __shared__ float sxy, swh, scls;
    if (tid == 0) { sxy = 0.f; swh = 0.f; scls = 0.f; }
    if (tid < CIN) xs[tid] = x[((size_t)b*CIN + tid)*FF + pos];
    __syncthreads();

    if (tid < NCH*3) {
      const int c = tid/3, ks = tid%3;
      const int kb = ks*86;
      const int ke = (kb+86 < CIN) ? kb+86 : CIN;
      const float* __restrict__ wr = W + (size_t)(a*NCH + c)*CIN;
      float p = 0.f;
      for (int k=kb;k<ke;++k) p = fmaf(xs[k], wr[k], p);
      sdot[tid] = p;
    }
    __syncthreads();

    if (tid < NCH) {
      const float z = sdot[tid*3] + sdot[tid*3+1] + sdot[tid*3+2] + bias[a*NCH + tid];
      const float scale = sqrtf(2.f - ti.gw*ti.gh/(float)(FW*FW));
      if (tid < 2) {
        const float tv = (tid==0) ? (ti.gx - floorf(ti.gx)) : (ti.gy - floorf(ti.gy));
        const float p  = sigmoidf_(z);
        const float term = tv*clogf_(p) + (1.f-tv)*clogf_(1.f-p);
        atomicAdd(&sxy, -term*scale*scale);
      } else if (tid < 4) {
        const float anch = (tid==2) ? c_aw[a] : c_ah[a];
        const float g    = (tid==2) ? ti.gw  : ti.gh;
        const float tv   = logf(g/anch + 1e-16f);
        const float d    = (z - tv)*scale;
        atomicAdd(&swh, 0.5f*d*d);
      } else if (tid >= 5) {
        const float tv = ((tid-5) == ti.cls) ? 1.f : 0.f;
        const float p  = sigmoidf_(z);
        const float term = tv*clogf_(p) + (1.f-tv)*clogf_(1.f-p);
        atomicAdd(&scls, -term);
      }
    }
    __syncthreads();
    if (tid == 0) {
      atomicAdd(accum+0, (double)sxy);
      atomicAdd(accum+1, (double)swh);
      atomicAdd(accum+3, (double)scls);
    }
  }
}

__global__ void yolo_init(double* __restrict__ accum){
  if (threadIdx.x < 4) accum[threadIdx.x] = 0.0;
}

__global__ void yolo_fin(const double* __restrict__ accum, float* __restrict__ out){
  if (threadIdx.x == 0) {
    float fxy  = (float)accum[0];
    float fwh  = (float)accum[1];
    float fobj = (float)accum[2];
    float fcls = (float)accum[3];
    out[0] = fxy + fwh + fobj + fcls;
    out[1] = fxy;
    out[2] = fwh;
    out[3] = fobj;
    out[4] = fcls;
  }
}

extern "C" void kernel_launch(void* const* d_in, const int* in_sizes, int n_in,
                              void* d_out, int out_size, void* d_ws, size_t ws_size,
                              hipStream_t stream) {
  const float* x    = (const float*)d_in[0];
  const float* tg   = (const float*)d_in[1];
  const float* W    = (const float*)d_in[2];
  const float* bias = (const float*)d_in[3];
  float*  out   = (float*)d_out;
  double* accum = (double*)d_ws;

  hipLaunchKernelGGL(yolo_init, dim3(1), dim3(64), 0, stream, accum);
  hipLaunchKernelGGL(yolo_fused, dim3(CONV_BLOCKS + TGT_BLOCKS), dim3(POSB), 0, stream,
                     x, tg, W, bias, accum);
  hipLaunchKernelGGL(yolo_fin, dim3(1), dim3(64), 0, stream, accum, out);
}

// Round 6
// 207.314 us; speedup vs baseline: 1.0311x; 1.0311x over previous
//
#include <hip/hip_runtime.h>
#include <math.h>

#define NB   16
#define CIN  256
#define FW   76
#define FF   (FW*FW)          // 5776
#define NT   50
#define NA   3
#define NCH  85               // 80 classes + 5
#define POSB 256
#define NCONV ((FF + POSB - 1)/POSB)   // 23
#define CONV_BLOCKS (NB*NCONV)         // 368
#define TGT_BLOCKS  (NB*NT)            // 800
#define TOT_BLOCKS  (CONV_BLOCKS + TGT_BLOCKS)
#define KT   32
#define NCHUNK (CIN/KT)       // 8

__device__ __constant__ float c_aw[9] = {1.25f,2.0f,4.125f,3.75f,7.75f,7.375f,14.5f,19.5f,46.625f};
__device__ __constant__ float c_ah[9] = {1.625f,3.75f,2.875f,7.625f,5.625f,14.875f,11.25f,24.75f,40.75f};

__device__ inline float clogf_(float z){
  return (z > 0.f) ? fmaxf(logf(z), -100.f) : -100.f;
}
__device__ inline float sigmoidf_(float z){
  return 1.f/(1.f + expf(-z));
}

// async global->LDS, 16B per lane. dst must be wave-uniform; HW adds lane*16.
__device__ __forceinline__ void gload_lds16(const float* src, float* dst){
  __builtin_amdgcn_global_load_lds(
      (const __attribute__((address_space(1))) void*)src,
      (__attribute__((address_space(3))) void*)dst, 16, 0, 0);
}

struct TInfo {
  int valid, keep, la, gxi, gyi, cls;
  float gx, gy, gw, gh;
};

__device__ inline TInfo make_tinfo(const float* __restrict__ tg, int b, int t){
  const float* p = tg + ((size_t)b*NT + t)*5;
  float x=p[0], y=p[1], w=p[2], h=p[3], c=p[4];
  TInfo r;
  r.valid = (x+y+w+h+c) > 0.f ? 1 : 0;
  r.gx = x*(float)FW; r.gy = y*(float)FW; r.gw = w*(float)FW; r.gh = h*(float)FW;
  r.gxi = (int)r.gx; r.gyi = (int)r.gy;
  r.cls = (int)c;
  int best=0; float br=-1.f;
  #pragma unroll
  for (int i=0;i<9;++i){
    float inter = fminf(r.gw, c_aw[i]) * fminf(r.gh, c_ah[i]);
    float uni = r.gw*r.gh + c_aw[i]*c_ah[i] - inter;
    float rt = inter/(uni + 1e-16f);
    if (rt > br){ br = rt; best = i; }
  }
  r.la = best;
  r.keep = (r.valid && best < NA) ? 1 : 0;
  return r;
}

__global__ __launch_bounds__(256) void yolo_fused(
    const float* __restrict__ x, const float* __restrict__ tg,
    const float* __restrict__ W, const float* __restrict__ bias,
    double* __restrict__ part)
{
  const int bid = blockIdx.x;
  const int tid = threadIdx.x;

  if (bid < CONV_BLOCKS) {
    // ---------- dense pass: obj loss over all cells (only 15 conv channels) ----------
    __shared__ float xbuf[2][KT][POSB];       // 64 KB double-buffered x tile [k][pos]
    __shared__ float s_x1[NT], s_y1[NT], s_x2[NT], s_y2[NT], s_area[NT];
    __shared__ int   s_val[NT], s_code[NT];
    __shared__ int   s_nt;
    __shared__ float s_red[POSB];

    const int b    = bid / NCONV;
    const int chunk= bid % NCONV;
    const int pos0 = chunk*POSB;
    const int pos  = pos0 + tid;
    const bool act = pos < FF;

    int myvalid = 0;
    if (tid < NT) {
      TInfo ti = make_tinfo(tg, b, tid);
      myvalid = ti.valid;
      s_val[tid]  = ti.valid;
      s_x1[tid]   = ti.gx - 0.5f*ti.gw;
      s_x2[tid]   = ti.gx + 0.5f*ti.gw;
      s_y1[tid]   = ti.gy - 0.5f*ti.gh;
      s_y2[tid]   = ti.gy + 0.5f*ti.gh;
      s_area[tid] = ti.gw*ti.gh;
      s_code[tid] = ti.keep ? (ti.la*FF + ti.gyi*FW + ti.gxi) : -1;
    }
    if (tid < 64) {
      unsigned long long m = __ballot(myvalid != 0);
      if (tid == 0) s_nt = __popcll(m);
    }

    // per-lane global source: 16B (4 positions), clamped to stay in-image
    const int lane = tid & 63;
    const int w    = tid >> 6;
    int srcpos = pos0 + lane*4;
    if (srcpos > FF-4) srcpos = FF-4;      // tail chunk: duplicate, masked by act
    const float* xsrc = x + (size_t)b*CIN*FF + srcpos;

    // prologue: stage chunk 0 -> buf 0 (wave w stages k-rows w*8..w*8+7)
    #pragma unroll
    for (int j=0;j<8;++j){
      const int krow = w*8 + j;
      gload_lds16(xsrc + (size_t)krow*FF, &xbuf[0][krow][0]);
    }
    __syncthreads();   // drains vmcnt + covers target-LDS writes

    float acc[NA][5];
    #pragma unroll
    for (int a=0;a<NA;++a)
      #pragma unroll
      for (int c=0;c<5;++c) acc[a][c] = 0.f;

    int cb = 0;
    for (int c=0;c<NCHUNK;++c){
      if (c+1 < NCHUNK){
        const int k0n = (c+1)*KT;
        #pragma unroll
        for (int j=0;j<8;++j){
          const int krow = w*8 + j;
          gload_lds16(xsrc + (size_t)(k0n+krow)*FF, &xbuf[cb^1][krow][0]);
        }
      }
      const int k0 = c*KT;
      #pragma unroll 8
      for (int kk=0; kk<KT; ++kk){
        const float xv = xbuf[cb][kk][tid];
        const int k = k0 + kk;
        #pragma unroll
        for (int a=0;a<NA;++a)
          #pragma unroll
          for (int ch=0;ch<5;++ch)
            acc[a][ch] = fmaf(xv, W[(size_t)(a*NCH+ch)*CIN + k], acc[a][ch]);
      }
      __syncthreads();   // vmcnt(0)+barrier: next buffer ready, this one reusable
      cb ^= 1;
    }

    float lobj = 0.f;
    if (act) {
      const int gx = pos % FW;
      const int gy = pos / FW;
      #pragma unroll
      for (int a=0;a<NA;++a) {
        const float z0 = acc[a][0] + bias[a*NCH+0];
        const float z1 = acc[a][1] + bias[a*NCH+1];
        const float z2 = acc[a][2] + bias[a*NCH+2];
        const float z3 = acc[a][3] + bias[a*NCH+3];
        const float z4 = acc[a][4] + bias[a*NCH+4];
        const float s0 = sigmoidf_(z0);
        const float s1 = sigmoidf_(z1);
        const float s4 = sigmoidf_(z4);
        const float px = s0 + (float)gx;
        const float py = s1 + (float)gy;
        const float pw = expf(z2)*c_aw[a];
        const float ph = expf(z3)*c_ah[a];
        const float px1 = px - 0.5f*pw, px2 = px + 0.5f*pw;
        const float py1 = py - 0.5f*ph, py2 = py + 0.5f*ph;
        const float parea = pw*ph;
        bool high = false, ist = false;
        const int code = a*FF + pos;
        for (int t=0;t<NT;++t) {
          if (s_val[t]) {
            float iw = fminf(px2, s_x2[t]) - fmaxf(px1, s_x1[t]); iw = fmaxf(iw, 0.f);
            float ih = fminf(py2, s_y2[t]) - fmaxf(py1, s_y1[t]); ih = fmaxf(ih, 0.f);
            float ia = iw*ih;
            float iou = ia / (parea + s_area[t] - ia + 1e-16f);
            high = high || (iou > 0.7f);
          }
          ist = ist || (s_code[t] == code);
        }
        float mask = ist ? 1.f : ((a < s_nt) ? (high ? 0.f : 1.f) : 1.f);
        if (mask != 0.f)
          lobj -= ist ? clogf_(s4) : clogf_(1.f - s4);
      }
    }

    s_red[tid] = lobj;
    __syncthreads();
    #pragma unroll
    for (int s=POSB/2; s>0; s>>=1) {
      if (tid < s) s_red[tid] += s_red[tid+s];
      __syncthreads();
    }
    if (tid == 0) {
      double* p = part + (size_t)bid*4;
      p[0] = 0.0; p[1] = 0.0; p[2] = (double)s_red[0]; p[3] = 0.0;
    }

  } else {
    // ---------- target pass: xy/wh/cls at the <=800 target cells ----------
    const int idx = bid - CONV_BLOCKS;
    const int b = idx / NT, t = idx % NT;
    TInfo ti = make_tinfo(tg, b, t);   // block-uniform

    __shared__ float xs[CIN];
    __shared__ float sdot[NCH*3];
    __shared__ float sxy, swh, scls;
    if (tid == 0) { sxy = 0.f; swh = 0.f; scls = 0.f; }
    __syncthreads();

    if (ti.keep) {
      const int a   = ti.la;
      const int pos = ti.gyi*FW + ti.gxi;
      if (tid < CIN) xs[tid] = x[((size_t)b*CIN + tid)*FF + pos];
      __syncthreads();

      if (tid < NCH*3) {
        const int c = tid/3, ks = tid%3;
        const int kb = ks*86;
        const int ke = (kb+86 < CIN) ? kb+86 : CIN;
        const float* __restrict__ wr = W + (size_t)(a*NCH + c)*CIN;
        float p = 0.f;
        for (int k=kb;k<ke;++k) p = fmaf(xs[k], wr[k], p);
        sdot[tid] = p;
      }
      __syncthreads();

      if (tid < NCH) {
        const float z = sdot[tid*3] + sdot[tid*3+1] + sdot[tid*3+2] + bias[a*NCH + tid];
        const float scale = sqrtf(2.f - ti.gw*ti.gh/(float)(FW*FW));
        if (tid < 2) {
          const float tv = (tid==0) ? (ti.gx - floorf(ti.gx)) : (ti.gy - floorf(ti.gy));
          const float p  = sigmoidf_(z);
          const float term = tv*clogf_(p) + (1.f-tv)*clogf_(1.f-p);
          atomicAdd(&sxy, -term*scale*scale);
        } else if (tid < 4) {
          const float anch = (tid==2) ? c_aw[a] : c_ah[a];
          const float g    = (tid==2) ? ti.gw  : ti.gh;
          const float tv   = logf(g/anch + 1e-16f);
          const float d    = (z - tv)*scale;
          atomicAdd(&swh, 0.5f*d*d);
        } else if (tid >= 5) {
          const float tv = ((tid-5) == ti.cls) ? 1.f : 0.f;
          const float p  = sigmoidf_(z);
          const float term = tv*clogf_(p) + (1.f-tv)*clogf_(1.f-p);
          atomicAdd(&scls, -term);
        }
      }
      __syncthreads();
    }

    if (tid == 0) {
      double* p = part + (size_t)bid*4;
      p[0] = (double)sxy; p[1] = (double)swh; p[2] = 0.0; p[3] = (double)scls;
    }
  }
}

__global__ void yolo_fin(const double* __restrict__ part, float* __restrict__ out){
  __shared__ double red[256];
  const int tid = threadIdx.x;
  double s = 0.0;
  for (int i = tid>>2; i < TOT_BLOCKS; i += 64)
    s += part[(size_t)i*4 + (tid&3)];
  red[tid] = s;
  __syncthreads();
  #pragma unroll
  for (int st=128; st>=4; st>>=1) {
    if (tid < st) red[tid] += red[tid+st];
    __syncthreads();
  }
  if (tid == 0) {
    float fxy  = (float)red[0];
    float fwh  = (float)red[1];
    float fobj = (float)red[2];
    float fcls = (float)red[3];
    out[0] = fxy + fwh + fobj + fcls;
    out[1] = fxy;
    out[2] = fwh;
    out[3] = fobj;
    out[4] = fcls;
  }
}

extern "C" void kernel_launch(void* const* d_in, const int* in_sizes, int n_in,
                              void* d_out, int out_size, void* d_ws, size_t ws_size,
                              hipStream_t stream) {
  const float* x    = (const float*)d_in[0];
  const float* tg   = (const float*)d_in[1];
  const float* W    = (const float*)d_in[2];
  const float* bias = (const float*)d_in[3];
  float*  out  = (float*)d_out;
  double* part = (double*)d_ws;   // [TOT_BLOCKS][4] partial sums

  hipLaunchKernelGGL(yolo_fused, dim3(TOT_BLOCKS), dim3(POSB), 0, stream,
                     x, tg, W, bias, part);
  hipLaunchKernelGGL(yolo_fin, dim3(1), dim3(256), 0, stream, part, out);
}

// Round 7
// 196.488 us; speedup vs baseline: 1.0879x; 1.0551x over previous
//
#include <hip/hip_runtime.h>
#include <math.h>

#define NB   16
#define CIN  256
#define FW   76
#define FF   (FW*FW)              // 5776
#define NT   50
#define NA   3
#define NCH  85                   // 80 classes + 5
#define PB   128                  // positions per dense block
#define NPOSC ((FF + PB - 1)/PB)  // 46
#define DENSE_BLOCKS (NB*NPOSC)   // 736
#define TGT_BLOCKS  (NB*NT)       // 800
#define TOT_BLOCKS  (DENSE_BLOCKS + TGT_BLOCKS)
#define KT   32
#define NCHUNK (CIN/KT)           // 8

__device__ __constant__ float c_aw[9] = {1.25f,2.0f,4.125f,3.75f,7.75f,7.375f,14.5f,19.5f,46.625f};
__device__ __constant__ float c_ah[9] = {1.625f,3.75f,2.875f,7.625f,5.625f,14.875f,11.25f,24.75f,40.75f};

__device__ inline float clogf_(float z){
  return (z > 0.f) ? fmaxf(logf(z), -100.f) : -100.f;
}
__device__ inline float sigmoidf_(float z){
  return 1.f/(1.f + expf(-z));
}

// async global->LDS, 16B per lane. LDS dst wave-uniform; HW adds lane*16.
// Global src IS per-lane.
__device__ __forceinline__ void gload_lds16(const float* src, float* dst){
  __builtin_amdgcn_global_load_lds(
      (const __attribute__((address_space(1))) void*)src,
      (__attribute__((address_space(3))) void*)dst, 16, 0, 0);
}

struct TInfo {
  int valid, keep, la, gxi, gyi, cls;
  float gx, gy, gw, gh;
};

__device__ inline TInfo make_tinfo(const float* __restrict__ tg, int b, int t){
  const float* p = tg + ((size_t)b*NT + t)*5;
  float x=p[0], y=p[1], w=p[2], h=p[3], c=p[4];
  TInfo r;
  r.valid = (x+y+w+h+c) > 0.f ? 1 : 0;
  r.gx = x*(float)FW; r.gy = y*(float)FW; r.gw = w*(float)FW; r.gh = h*(float)FW;
  r.gxi = (int)r.gx; r.gyi = (int)r.gy;
  r.cls = (int)c;
  int best=0; float br=-1.f;
  #pragma unroll
  for (int i=0;i<9;++i){
    float inter = fminf(r.gw, c_aw[i]) * fminf(r.gh, c_ah[i]);
    float uni = r.gw*r.gh + c_aw[i]*c_ah[i] - inter;
    float rt = inter/(uni + 1e-16f);
    if (rt > br){ br = rt; best = i; }
  }
  r.la = best;
  r.keep = (r.valid && best < NA) ? 1 : 0;
  return r;
}

__global__ __launch_bounds__(256) void yolo_fused(
    const float* __restrict__ x, const float* __restrict__ tg,
    const float* __restrict__ W, const float* __restrict__ bias,
    double* __restrict__ part)
{
  const int bid = blockIdx.x;
  const int tid = threadIdx.x;

  if (bid < DENSE_BLOCKS) {
    // ---------- dense pass: obj loss over all cells (15 conv channels) ----------
    // 256 threads = 128 positions x 2 k-halves (k-split doubles wave count vs 1 thr/pos)
    __shared__ float smem[2*KT*PB];   // 32 KB: dbuf x-tile [buf][k][pos]; reused as comb[2][15][PB]
    __shared__ float s_x1[NT], s_y1[NT], s_x2[NT], s_y2[NT], s_area[NT];
    __shared__ int   s_kcode[NT];
    __shared__ int   s_nv, s_nk;
    __shared__ float s_red[256];

    const int b    = bid / NPOSC;
    const int pos0 = (bid % NPOSC)*PB;
    const int p    = tid & (PB-1);
    const int h    = tid >> 7;        // k-half: waves 0,1 -> h=0; waves 2,3 -> h=1
    const int pos  = pos0 + p;
    const bool act = pos < FF;

    // target prep + compaction (wave 0 only; NT=50 <= 64)
    if (tid < 64) {
      TInfo ti; ti.valid = 0; ti.keep = 0;
      if (tid < NT) ti = make_tinfo(tg, b, tid);
      unsigned long long vm = __ballot(ti.valid != 0);
      unsigned long long km = __ballot(ti.keep  != 0);
      unsigned long long lt = (1ull << tid) - 1ull;
      if (ti.valid) {
        int s = __popcll(vm & lt);
        s_x1[s]   = ti.gx - 0.5f*ti.gw;
        s_x2[s]   = ti.gx + 0.5f*ti.gw;
        s_y1[s]   = ti.gy - 0.5f*ti.gh;
        s_y2[s]   = ti.gy + 0.5f*ti.gh;
        s_area[s] = ti.gw*ti.gh;
      }
      if (ti.keep) {
        int s = __popcll(km & lt);
        s_kcode[s] = ti.la*FF + ti.gyi*FW + ti.gxi;
      }
      if (tid == 0) { s_nv = __popcll(vm); s_nk = __popcll(km); }
    }

    // staging geometry: wave wv stages rows wv*8..wv*8+7, 2 rows per gload (lane>>5),
    // cols (lane&31)*4, clamped to row end (dups masked by act)
    const int lane = tid & 63;
    const int wv   = tid >> 6;
    int cc = pos0 + (lane & 31)*4;
    if (cc > FF-4) cc = FF-4;
    const int rl = lane >> 5;
    const float* xbase = x + (size_t)b*CIN*FF + cc;

    // prologue: chunk 0 -> buf 0
    #pragma unroll
    for (int j=0;j<4;++j){
      const int row = wv*8 + j*2;
      gload_lds16(xbase + (size_t)(row + rl)*FF, &smem[row*PB]);
    }
    __syncthreads();   // vmcnt(0) drain + covers compaction writes

    float acc[NA][5];
    #pragma unroll
    for (int a=0;a<NA;++a)
      #pragma unroll
      for (int c=0;c<5;++c) acc[a][c] = 0.f;

    int cb = 0;
    for (int c=0;c<NCHUNK;++c){
      if (c+1 < NCHUNK){
        const int k0n = (c+1)*KT;
        const int bo  = (cb^1)*(KT*PB);
        #pragma unroll
        for (int j=0;j<4;++j){
          const int row = wv*8 + j*2;
          gload_lds16(xbase + (size_t)(k0n + row + rl)*FF, &smem[bo + row*PB]);
        }
      }
      // this thread computes its k-half of the chunk: rows h*16..h*16+15
      const int base = cb*(KT*PB) + (h*16)*PB + p;
      const int k0   = c*KT + h*16;
      #pragma unroll
      for (int kk=0; kk<16; ++kk){
        const float xv = smem[base + kk*PB];
        const int k = k0 + kk;
        #pragma unroll
        for (int a=0;a<NA;++a)
          #pragma unroll
          for (int ch=0;ch<5;++ch)
            acc[a][ch] = fmaf(xv, W[(size_t)(a*NCH+ch)*CIN + k], acc[a][ch]);
      }
      __syncthreads();
      cb ^= 1;
    }

    // combine k-halves via LDS (reuse smem; all xbuf reads done after final sync)
    #pragma unroll
    for (int a=0;a<NA;++a)
      #pragma unroll
      for (int ch=0;ch<5;++ch)
        smem[h*(15*PB) + (a*5+ch)*PB + p] = acc[a][ch];
    __syncthreads();

    // epilogue: 384 (pos,anchor) items on 256 threads:
    // tid<128 -> anchors {0,2} for pos p; tid>=128 -> anchor {1} for pos p
    float lobj = 0.f;
    if (act) {
      const int gx = pos % FW;
      const int gy = pos / FW;
      const int a0 = (tid < 128) ? 0 : 1;
      const int na = (tid < 128) ? 2 : 1;
      for (int ai=0; ai<na; ++ai) {
        const int a = a0 + ai*2;
        float z[5];
        #pragma unroll
        for (int ch=0;ch<5;++ch)
          z[ch] = smem[(a*5+ch)*PB + p] + smem[15*PB + (a*5+ch)*PB + p] + bias[a*NCH+ch];
        const float s0 = sigmoidf_(z[0]);
        const float s1 = sigmoidf_(z[1]);
        const float s4 = sigmoidf_(z[4]);
        const float px = s0 + (float)gx;
        const float py = s1 + (float)gy;
        const float pw = expf(z[2])*c_aw[a];
        const float ph = expf(z[3])*c_ah[a];
        const float px1 = px - 0.5f*pw, px2 = px + 0.5f*pw;
        const float py1 = py - 0.5f*ph, py2 = py + 0.5f*ph;
        const float parea = pw*ph;
        bool high = false;
        for (int j=0;j<s_nv;++j) {
          float iw = fminf(px2, s_x2[j]) - fmaxf(px1, s_x1[j]); iw = fmaxf(iw, 0.f);
          float ih = fminf(py2, s_y2[j]) - fmaxf(py1, s_y1[j]); ih = fmaxf(ih, 0.f);
          float ia = iw*ih;
          float iou = ia / (parea + s_area[j] - ia + 1e-16f);
          high = high || (iou > 0.7f);
        }
        bool ist = false;
        const int code = a*FF + pos;
        for (int j=0;j<s_nk;++j) ist = ist || (s_kcode[j] == code);
        float mask = ist ? 1.f : ((a < s_nv) ? (high ? 0.f : 1.f) : 1.f);
        if (mask != 0.f)
          lobj -= ist ? clogf_(s4) : clogf_(1.f - s4);
      }
    }

    s_red[tid] = lobj;
    __syncthreads();
    #pragma unroll
    for (int s=128; s>0; s>>=1) {
      if (tid < s) s_red[tid] += s_red[tid+s];
      __syncthreads();
    }
    if (tid == 0) {
      double* q = part + (size_t)bid*4;
      q[0] = 0.0; q[1] = 0.0; q[2] = (double)s_red[0]; q[3] = 0.0;
    }

  } else {
    // ---------- target pass: xy/wh/cls at the <=800 target cells ----------
    const int idx = bid - DENSE_BLOCKS;
    const int b = idx / NT, t = idx % NT;
    TInfo ti = make_tinfo(tg, b, t);   // block-uniform

    __shared__ float xs[CIN];
    __shared__ float sdot[NCH*3];
    __shared__ float sxy, swh, scls;
    if (tid == 0) { sxy = 0.f; swh = 0.f; scls = 0.f; }
    __syncthreads();

    if (ti.keep) {
      const int a   = ti.la;
      const int pos = ti.gyi*FW + ti.gxi;
      if (tid < CIN) xs[tid] = x[((size_t)b*CIN + tid)*FF + pos];
      __syncthreads();

      if (tid < NCH*3) {
        const int c = tid/3, ks = tid%3;
        const int kb = ks*86;
        const int ke = (kb+86 < CIN) ? kb+86 : CIN;
        const float* __restrict__ wr = W + (size_t)(a*NCH + c)*CIN;
        float pr = 0.f;
        for (int k=kb;k<ke;++k) pr = fmaf(xs[k], wr[k], pr);
        sdot[tid] = pr;
      }
      __syncthreads();

      if (tid < NCH) {
        const float z = sdot[tid*3] + sdot[tid*3+1] + sdot[tid*3+2] + bias[a*NCH + tid];
        const float scale = sqrtf(2.f - ti.gw*ti.gh/(float)(FW*FW));
        if (tid < 2) {
          const float tv = (tid==0) ? (ti.gx - floorf(ti.gx)) : (ti.gy - floorf(ti.gy));
          const float pp = sigmoidf_(z);
          const float term = tv*clogf_(pp) + (1.f-tv)*clogf_(1.f-pp);
          atomicAdd(&sxy, -term*scale*scale);
        } else if (tid < 4) {
          const float anch = (tid==2) ? c_aw[a] : c_ah[a];
          const float g    = (tid==2) ? ti.gw  : ti.gh;
          const float tv   = logf(g/anch + 1e-16f);
          const float d    = (z - tv)*scale;
          atomicAdd(&swh, 0.5f*d*d);
        } else if (tid >= 5) {
          const float tv = ((tid-5) == ti.cls) ? 1.f : 0.f;
          const float pp = sigmoidf_(z);
          const float term = tv*clogf_(pp) + (1.f-tv)*clogf_(1.f-pp);
          atomicAdd(&scls, -term);
        }
      }
      __syncthreads();
    }

    if (tid == 0) {
      double* q = part + (size_t)bid*4;
      q[0] = (double)sxy; q[1] = (double)swh; q[2] = 0.0; q[3] = (double)scls;
    }
  }
}

__global__ void yolo_fin(const double* __restrict__ part, float* __restrict__ out){
  __shared__ double red[256];
  const int tid = threadIdx.x;
  double s = 0.0;
  for (int i = tid>>2; i < TOT_BLOCKS; i += 64)
    s += part[(size_t)i*4 + (tid&3)];
  red[tid] = s;
  __syncthreads();
  #pragma unroll
  for (int st=128; st>=4; st>>=1) {
    if (tid < st) red[tid] += red[tid+st];
    __syncthreads();
  }
  if (tid == 0) {
    float fxy  = (float)red[0];
    float fwh  = (float)red[1];
    float fobj = (float)red[2];
    float fcls = (float)red[3];
    out[0] = fxy + fwh + fobj + fcls;
    out[1] = fxy;
    out[2] = fwh;
    out[3] = fobj;
    out[4] = fcls;
  }
}

extern "C" void kernel_launch(void* const* d_in, const int* in_sizes, int n_in,
                              void* d_out, int out_size, void* d_ws, size_t ws_size,
                              hipStream_t stream) {
  const float* x    = (const float*)d_in[0];
  const float* tg   = (const float*)d_in[1];
  const float* W    = (const float*)d_in[2];
  const float* bias = (const float*)d_in[3];
  float*  out  = (float*)d_out;
  double* part = (double*)d_ws;   // [TOT_BLOCKS][4] partial sums

  hipLaunchKernelGGL(yolo_fused, dim3(TOT_BLOCKS), dim3(256), 0, stream,
                     x, tg, W, bias, part);
  hipLaunchKernelGGL(yolo_fin, dim3(1), dim3(256), 0, stream, part, out);
}